// Round 1
// baseline (60.347 us; speedup 1.0000x reference)
//
#include <hip/hip_runtime.h>

#define NV 5
#define NB 4
#define NJ 15
#define HMW 128
#define HMH 128
#define P_TOTAL (64 * 64 * 64)        // 262144 points per batch
#define HM_PLANE (HMH * HMW)          // 16384
#define CUBES_ELEMS ((size_t)NB * NJ * P_TOTAL)

__global__ __launch_bounds__(256) void project_layer_kernel(
    const float* __restrict__ hm,      // (NV, NB, NJ, 128, 128)
    const float* __restrict__ projM,   // (NV, NB, 3, 4)
    const float* __restrict__ center,  // (NB, 3)
    const int*   __restrict__ gsize,   // scalar
    float* __restrict__ out)           // cubes | grids
{
    const int blk = blockIdx.x;
    const int b   = blk >> 10;                       // 1024 blocks per batch
    const int p   = ((blk & 1023) << 8) | threadIdx.x;
    const int gi  = p >> 12;
    const int gj  = (p >> 6) & 63;
    const int gk  = p & 63;

    const float gs   = (float)gsize[0];
    const float half = gs * 0.5f;
    const float step = gs / 63.0f;                   // (stop-start)/div

    const float cx = center[b * 3 + 0];
    const float cy = center[b * 3 + 1];
    const float cz = center[b * 3 + 2];

    // numpy linspace forces the endpoint exactly
    const float gx = ((gi == 63) ? half : fmaf((float)gi, step, -half)) + cx;
    const float gy = ((gj == 63) ? half : fmaf((float)gj, step, -half)) + cy;
    const float gz = ((gk == 63) ? half : fmaf((float)gk, step, -half)) + cz;

    float num[NJ];
#pragma unroll
    for (int j = 0; j < NJ; ++j) num[j] = 0.0f;
    float cnt = 0.0f;

    for (int n = 0; n < NV; ++n) {
        const float* M = projM + ((size_t)(n * NB + b)) * 12;
        // homog = [x, z, y, 1]
        const float px = M[0] * gx + M[1] * gz + M[2]  * gy + M[3];
        const float py = M[4] * gx + M[5] * gz + M[6]  * gy + M[7];
        const float pz = M[8] * gx + M[9] * gz + M[10] * gy + M[11];

        const float u = px / pz;
        const float v = py / pz;

        // NaN/inf comparisons are false -> view skipped, matches reference
        const bool inb = (u >= 0.0f) && (v >= 0.0f) && (u < 512.0f) && (v < 512.0f);
        if (!inb) continue;

        cnt += 1.0f;

        // scale to heatmap coords, then to [-1,1] sample grid, then to pixel
        const float u2 = u * 0.25f;                  // * HM_W / IMG_W
        const float v2 = v * 0.25f;
        const float sx = (u2 / 127.0f) * 2.0f - 1.0f;   // clip(-1.1,1.1) is a no-op when inb
        const float sy = (v2 / 127.0f) * 2.0f - 1.0f;
        const float ix = (sx + 1.0f) * 0.5f * 127.0f;
        const float iy = (sy + 1.0f) * 0.5f * 127.0f;

        const float x0f = floorf(ix);
        const float y0f = floorf(iy);
        const float wx1 = ix - x0f, wx0 = 1.0f - wx1;
        const float wy1 = iy - y0f, wy0 = 1.0f - wy1;
        const float x1f = x0f + 1.0f, y1f = y0f + 1.0f;

        const float vx0 = (x0f >= 0.0f && x0f <= 127.0f) ? 1.0f : 0.0f;
        const float vx1 = (x1f >= 0.0f && x1f <= 127.0f) ? 1.0f : 0.0f;
        const float vy0 = (y0f >= 0.0f && y0f <= 127.0f) ? 1.0f : 0.0f;
        const float vy1 = (y1f >= 0.0f && y1f <= 127.0f) ? 1.0f : 0.0f;

        const int x0 = (int)fminf(fmaxf(x0f, 0.0f), 127.0f);
        const int x1 = (int)fminf(fmaxf(x1f, 0.0f), 127.0f);
        const int y0 = (int)fminf(fmaxf(y0f, 0.0f), 127.0f);
        const int y1 = (int)fminf(fmaxf(y1f, 0.0f), 127.0f);

        const float w00 = (wx0 * wy0) * (vx0 * vy0);
        const float w10 = (wx1 * wy0) * (vx1 * vy0);
        const float w01 = (wx0 * wy1) * (vx0 * vy1);
        const float w11 = (wx1 * wy1) * (vx1 * vy1);

        const int o00 = y0 * HMW + x0;
        const int o10 = y0 * HMW + x1;
        const int o01 = y1 * HMW + x0;
        const int o11 = y1 * HMW + x1;

        const float* img = hm + ((size_t)(n * NB + b) * NJ) * HM_PLANE;
#pragma unroll
        for (int j = 0; j < NJ; ++j) {
            const float* ij = img + (size_t)j * HM_PLANE;
            // same corner summation order as reference
            num[j] += w00 * ij[o00] + w10 * ij[o10] + w01 * ij[o01] + w11 * ij[o11];
        }
    }

    const float den = cnt + 1e-6f;

    // cubes: (B, J, P) — coalesced per-j stores
    {
        float* cb = out + (size_t)b * NJ * P_TOTAL + p;
#pragma unroll
        for (int j = 0; j < NJ; ++j) {
            const float c = num[j] / den;            // true division, like ref
            cb[(size_t)j * P_TOTAL] = fminf(fmaxf(c, 0.0f), 1.0f);
        }
    }

    // grids: (B, P, 3)
    {
        float* go = out + CUBES_ELEMS + ((size_t)b * P_TOTAL + p) * 3;
        go[0] = gx;
        go[1] = gy;
        go[2] = gz;
    }
}

extern "C" void kernel_launch(void* const* d_in, const int* in_sizes, int n_in,
                              void* d_out, int out_size, void* d_ws, size_t ws_size,
                              hipStream_t stream) {
    const float* hm     = (const float*)d_in[0];
    const float* projM  = (const float*)d_in[1];
    const float* center = (const float*)d_in[2];
    const int*   gsize  = (const int*)d_in[3];
    float* out = (float*)d_out;

    const int total_points = NB * P_TOTAL;           // 1,048,576
    const int blocks = total_points / 256;           // 4096
    project_layer_kernel<<<blocks, 256, 0, stream>>>(hm, projM, center, gsize, out);
}